// Round 2
// baseline (1193.231 us; speedup 1.0000x reference)
//
#include <hip/hip_runtime.h>

#define IN_DIM 256
#define HID 128
#define CAP 48       // bucket capacity per node; P(Poisson(16) >= 48) ~ 1e-30
                     // slice/partition = 12.5K nodes * 192B = 2.4MB < 4MB XCD L2
#define NPART 8      // dst partitions, one per XCD (blockIdx%8 -> XCD heuristic)
#define NCHUNK 128   // edge chunks per partition; grid = NPART*NCHUNK

using short8 = __attribute__((ext_vector_type(8))) short;
using f32x4  = __attribute__((ext_vector_type(4))) float;

// ---------------------------------------------------------------------------
// bf16 helpers (RNE round, bit-level — avoids type-plumbing issues)
// ---------------------------------------------------------------------------
__device__ __forceinline__ unsigned short f2bf(float x) {
    unsigned int u = __float_as_uint(x);
    u += 0x7fffu + ((u >> 16) & 1u);
    return (unsigned short)(u >> 16);
}
__device__ __forceinline__ float bf2f(unsigned short b) {
    return __uint_as_float((unsigned int)b << 16);
}

// ---------------------------------------------------------------------------
// int64-vs-int32 edge storage detect for all 3 graphs in one launch
// (edge values < 2^31 -> odd words all 0 -> mode 1)
// ---------------------------------------------------------------------------
__global__ void detect3_k(const int* __restrict__ a, const int* __restrict__ b,
                          const int* __restrict__ c, int n_check,
                          int* __restrict__ modes) {
    const int* e = (blockIdx.x == 0) ? a : (blockIdx.x == 1) ? b : c;
    __shared__ int any_nz;
    if (threadIdx.x == 0) any_nz = 0;
    __syncthreads();
    for (int i = threadIdx.x; i < n_check; i += blockDim.x) {
        if (e[2 * i + 1] != 0) atomicOr(&any_nz, 1);
    }
    __syncthreads();
    if (threadIdx.x == 0) modes[blockIdx.x] = any_nz ? 0 : 1;
}

// ---------------------------------------------------------------------------
// dst/src-partitioned preprocessing, v2.
// R1 lesson: CAP=96 slice (4.8MB) exceeded the 4MB XCD L2 and the edge
// stream evicted dirty bucket lines -> WRITE_SIZE stayed ~130MB. Fix:
//   * CAP=48 -> slice 2.4MB, L2-resident on its XCD
//   * non-temporal edge loads (nt flag) -> stream doesn't evict bucket lines
// Dirty bucket lines should now write back once per touched line (~10MB).
// ---------------------------------------------------------------------------
__global__ __launch_bounds__(256) void preprocess_part_k(
        const int* __restrict__ e32, int E, const int* __restrict__ mode_p,
        int* __restrict__ deg_out, int* __restrict__ cnt,
        int* __restrict__ bucket, int N) {
    const int p  = blockIdx.x & (NPART - 1);   // partition -> XCD affinity
    const int c  = blockIdx.x / NPART;         // edge chunk
    const int PS = (N + NPART - 1) / NPART;
    const int lo = p * PS;
    const int hi = min(N, lo + PS);
    const int stride = NCHUNK * 256;
    const int mode = *mode_p;

    if (mode) {  // int64 storage, values fit in low word
        const long long* __restrict__ s64 = (const long long*)e32;
        const long long* __restrict__ d64 = s64 + E;
        for (int i = c * 256 + (int)threadIdx.x; i < E; i += stride) {
            int s = (int)__builtin_nontemporal_load(&s64[i]);
            int d = (int)__builtin_nontemporal_load(&d64[i]);
            if (s >= lo && s < hi) atomicAdd(&deg_out[s], 1);
            if (d >= lo && d < hi) {
                int pos = atomicAdd(&cnt[d], 1);
                if (pos < CAP) bucket[(size_t)d * CAP + pos] = s;
            }
        }
    } else {     // int32 storage
        const int* __restrict__ s32 = e32;
        const int* __restrict__ d32 = e32 + E;
        for (int i = c * 256 + (int)threadIdx.x; i < E; i += stride) {
            int s = __builtin_nontemporal_load(&s32[i]);
            int d = __builtin_nontemporal_load(&d32[i]);
            if (s >= lo && s < hi) atomicAdd(&deg_out[s], 1);
            if (d >= lo && d < hi) {
                int pos = atomicAdd(&cnt[d], 1);
                if (pos < CAP) bucket[(size_t)d * CAP + pos] = s;
            }
        }
    }
}

// ---------------------------------------------------------------------------
// bf16-split MFMA GEMM:
//   Hout[row][0:128] = bf16( (X[row][0:K] @ W[K][128]) * clip(deg,1)^-1/2 )
// X fp32 is split into hi/lo bf16 (x = hi + lo); 3 MFMA products per tile give
// fp32-class accuracy. BM=128, BN=128, BK=32; 4 waves, each owns a 64x64 tile
// as 4x4 fragments of 16x16 (mfma_f32_16x16x32_bf16).
// ---------------------------------------------------------------------------
__global__ __launch_bounds__(256) void gemm_split_k(const float* __restrict__ X,
                                                    const float* __restrict__ W,
                                                    const int* __restrict__ deg,
                                                    unsigned short* __restrict__ Hout,
                                                    int M, int K) {
    __shared__ __align__(16) unsigned short As_hi[128 * 32];
    __shared__ __align__(16) unsigned short As_lo[128 * 32];
    __shared__ __align__(16) unsigned short Bs_hi[128 * 32];
    __shared__ __align__(16) unsigned short Bs_lo[128 * 32];

    const int tid = threadIdx.x;
    const int lane = tid & 63;
    const int w = tid >> 6;
    const int wr = w >> 1, wc = w & 1;
    const int bm = blockIdx.x * 128;
    const int l15 = lane & 15, l4 = lane >> 4;

    f32x4 acc[4][4];
#pragma unroll
    for (int m = 0; m < 4; ++m)
#pragma unroll
        for (int n = 0; n < 4; ++n) acc[m][n] = (f32x4){0.f, 0.f, 0.f, 0.f};

    for (int k0 = 0; k0 < K; k0 += 32) {
        // ---- stage A (128 rows x 32 k, fp32 -> hi/lo bf16), coalesced float4 ----
#pragma unroll
        for (int i = 0; i < 4; ++i) {
            int idx = tid + i * 256;     // 0..1023 float4 slots
            int r = idx >> 3;            // row in tile
            int kq = idx & 7;            // float4 index within row
            float4 v = make_float4(0.f, 0.f, 0.f, 0.f);
            if (bm + r < M) v = *(const float4*)&X[(size_t)(bm + r) * K + k0 + kq * 4];
            ushort4 h, l;
            h.x = f2bf(v.x); l.x = f2bf(v.x - bf2f(h.x));
            h.y = f2bf(v.y); l.y = f2bf(v.y - bf2f(h.y));
            h.z = f2bf(v.z); l.z = f2bf(v.z - bf2f(h.z));
            h.w = f2bf(v.w); l.w = f2bf(v.w - bf2f(h.w));
            *(ushort4*)&As_hi[r * 32 + kq * 4] = h;
            *(ushort4*)&As_lo[r * 32 + kq * 4] = l;
        }
        // ---- stage B transposed: Bs[col][k] (reads of W are coalesced per j) ----
        {
            int col = tid & 127;
            int kh = tid >> 7;  // 0..1 -> k-halves of 16
            unsigned short hi[16], lo[16];
#pragma unroll
            for (int j = 0; j < 16; ++j) {
                float v = W[(size_t)(k0 + kh * 16 + j) * 128 + col];
                hi[j] = f2bf(v);
                lo[j] = f2bf(v - bf2f(hi[j]));
            }
            short8 ph0, ph1, pl0, pl1;
#pragma unroll
            for (int j = 0; j < 8; ++j) {
                ph0[j] = (short)hi[j]; ph1[j] = (short)hi[j + 8];
                pl0[j] = (short)lo[j]; pl1[j] = (short)lo[j + 8];
            }
            *(short8*)&Bs_hi[col * 32 + kh * 16 + 0] = ph0;
            *(short8*)&Bs_hi[col * 32 + kh * 16 + 8] = ph1;
            *(short8*)&Bs_lo[col * 32 + kh * 16 + 0] = pl0;
            *(short8*)&Bs_lo[col * 32 + kh * 16 + 8] = pl1;
        }
        __syncthreads();

        // ---- fragment loads ----
        short8 ah[4], al[4], bh[4], bl[4];
#pragma unroll
        for (int m = 0; m < 4; ++m) {
            int row = wr * 64 + m * 16 + l15;
            ah[m] = *(const short8*)&As_hi[row * 32 + l4 * 8];
            al[m] = *(const short8*)&As_lo[row * 32 + l4 * 8];
        }
#pragma unroll
        for (int n = 0; n < 4; ++n) {
            int col = wc * 64 + n * 16 + l15;
            bh[n] = *(const short8*)&Bs_hi[col * 32 + l4 * 8];
            bl[n] = *(const short8*)&Bs_lo[col * 32 + l4 * 8];
        }

        // ---- MFMA: hi*hi + lo*hi + hi*lo ----
#pragma unroll
        for (int m = 0; m < 4; ++m)
#pragma unroll
            for (int n = 0; n < 4; ++n) {
                acc[m][n] = __builtin_amdgcn_mfma_f32_16x16x32_bf16(ah[m], bh[n], acc[m][n], 0, 0, 0);
                acc[m][n] = __builtin_amdgcn_mfma_f32_16x16x32_bf16(al[m], bh[n], acc[m][n], 0, 0, 0);
                acc[m][n] = __builtin_amdgcn_mfma_f32_16x16x32_bf16(ah[m], bl[n], acc[m][n], 0, 0, 0);
            }
        __syncthreads();
    }

    // ---- epilogue: scale by deg_out^{-1/2}, store bf16 ----
    // C/D layout: col = lane&15, row = (lane>>4)*4 + reg  [m89/m91-verified]
#pragma unroll
    for (int m = 0; m < 4; ++m) {
#pragma unroll
        for (int i = 0; i < 4; ++i) {
            int row = bm + wr * 64 + m * 16 + l4 * 4 + i;
            if (row < M) {
                int dg = deg[row];
                float sc = rsqrtf((float)(dg > 1 ? dg : 1));
#pragma unroll
                for (int n = 0; n < 4; ++n) {
                    int col = wc * 64 + n * 16 + l15;
                    Hout[(size_t)row * 128 + col] = f2bf(acc[m][n][i] * sc);
                }
            }
        }
    }
}

// ---------------------------------------------------------------------------
// SpMM over buckets: out[n][:] = (sum_j bf16h[bucket[n][j]][:]) * deg^-1/2 + b
// One 64-lane wave per node; lane owns dims {2*lane, 2*lane+1} via uint loads.
// ---------------------------------------------------------------------------
__global__ __launch_bounds__(256) void spmm_k(const int* __restrict__ cnt,
                                              const int* __restrict__ bucket,
                                              const unsigned int* __restrict__ h32,
                                              const float* __restrict__ bias,
                                              float* __restrict__ out,
                                              int do_relu, int N) {
    const int lane = threadIdx.x & 63;
    const int n = blockIdx.x * 4 + (threadIdx.x >> 6);
    if (n >= N) return;
    const int deg = cnt[n];
    const int e1 = deg < CAP ? deg : CAP;
    const int* __restrict__ bk = bucket + (size_t)n * CAP;
    float a0 = 0.f, a1 = 0.f;
    int e = 0;
    for (; e + 4 <= e1; e += 4) {
        int s0 = bk[e + 0], s1 = bk[e + 1], s2 = bk[e + 2], s3 = bk[e + 3];
        unsigned int v0 = h32[(size_t)s0 * 64 + lane];
        unsigned int v1 = h32[(size_t)s1 * 64 + lane];
        unsigned int v2 = h32[(size_t)s2 * 64 + lane];
        unsigned int v3 = h32[(size_t)s3 * 64 + lane];
        a0 += __uint_as_float(v0 << 16) + __uint_as_float(v1 << 16) +
              __uint_as_float(v2 << 16) + __uint_as_float(v3 << 16);
        a1 += __uint_as_float(v0 & 0xffff0000u) + __uint_as_float(v1 & 0xffff0000u) +
              __uint_as_float(v2 & 0xffff0000u) + __uint_as_float(v3 & 0xffff0000u);
    }
    for (; e < e1; ++e) {
        unsigned int v = h32[(size_t)bk[e] * 64 + lane];
        a0 += __uint_as_float(v << 16);
        a1 += __uint_as_float(v & 0xffff0000u);
    }
    float sc = rsqrtf((float)(deg > 1 ? deg : 1));
    float bx = bias[2 * lane], by = bias[2 * lane + 1];
    float r0 = a0 * sc + bx;
    float r1 = a1 * sc + by;
    if (do_relu) { r0 = fmaxf(r0, 0.f); r1 = fmaxf(r1, 0.f); }
    float2 o; o.x = r0; o.y = r1;
    *(float2*)&out[(size_t)n * 128 + 2 * lane] = o;
}

// ---------------------------------------------------------------------------
// launcher
// ---------------------------------------------------------------------------
extern "C" void kernel_launch(void* const* d_in, const int* in_sizes, int n_in,
                              void* d_out, int out_size, void* d_ws, size_t ws_size,
                              hipStream_t stream) {
    const int E = in_sizes[0] / 2;        // 1,600,000
    const int N = in_sizes[1] / IN_DIM;   // 100,000

    const float* W0 = (const float*)d_in[6];
    const float* b0 = (const float*)d_in[7];
    const float* W1 = (const float*)d_in[8];
    const float* b1 = (const float*)d_in[9];
    float* out = (float*)d_out;

    char* ws = (char*)d_ws;
    size_t off = 0;
    auto alloc = [&](size_t bytes) -> void* {
        void* p = ws + off;
        off += (bytes + 255) & ~(size_t)255;
        return p;
    };
    const size_t Nr = ((size_t)N * 4 + 255) & ~(size_t)255;  // rounded histogram size
    unsigned short* hbuf = (unsigned short*)alloc((size_t)N * HID * 2);  // bf16 h (gather src)
    float* x1    = (float*)alloc((size_t)N * HID * 4);                   // layer-1 activations fp32
    int* bucket  = (int*)alloc((size_t)N * CAP * 4);
    int* degcnt  = (int*)alloc(2 * Nr);   // [deg_out | cnt] adjacent -> single memset
    int* modes   = (int*)alloc(256);

    int* deg_out = degcnt;
    int* cnt     = (int*)((char*)degcnt + Nr);

    const int gemm_blocks = (N + 127) / 128;
    const int spmm_blocks = (N + 3) / 4;
    const int prep_blocks = NPART * NCHUNK;

    // one detect launch for all three graphs
    detect3_k<<<3, 256, 0, stream>>>((const int*)d_in[0], (const int*)d_in[2],
                                     (const int*)d_in[4], 2048, modes);

    for (int g = 0; g < 3; ++g) {
        const int* e32 = (const int*)d_in[g * 2];
        const float* X = (const float*)d_in[g * 2 + 1];
        float* zout = out + (size_t)g * N * HID;
        const int K1 = in_sizes[g * 2 + 1] / N;  // 256

        hipMemsetAsync(degcnt, 0, 2 * Nr, stream);
        preprocess_part_k<<<prep_blocks, 256, 0, stream>>>(e32, E, modes + g,
                                                           deg_out, cnt, bucket, N);

        // layer 1
        gemm_split_k<<<gemm_blocks, 256, 0, stream>>>(X, W0, deg_out, hbuf, N, K1);
        spmm_k<<<spmm_blocks, 256, 0, stream>>>(cnt, bucket, (const unsigned int*)hbuf, b0, x1, 1, N);

        // layer 2
        gemm_split_k<<<gemm_blocks, 256, 0, stream>>>(x1, W1, deg_out, hbuf, N, HID);
        spmm_k<<<spmm_blocks, 256, 0, stream>>>(cnt, bucket, (const unsigned int*)hbuf, b1, zout, 0, N);
    }
}

// Round 3
// 934.411 us; speedup vs baseline: 1.2770x; 1.2770x over previous
//
#include <hip/hip_runtime.h>

#define IN_DIM 256
#define HID 128
#define CAP 48        // bucket capacity per node; P(Poisson(16) >= 48) ~ 1e-30
#define RANGE 512     // nodes per bin (dst>>9); LDS adjacency 512*48*4 = 98KB
#define RSH 9
#define MAXB 256      // max bins supported (N <= 131072; also s fits 17 bits)
#define CAPB 10240    // per-bin edge capacity (~8163 avg, 25% slack)
#define CHUNK 4096    // edges per bin_k workgroup (256 thr * 16)

using short8 = __attribute__((ext_vector_type(8))) short;
using f32x4  = __attribute__((ext_vector_type(4))) float;

// ---------------------------------------------------------------------------
// bf16 helpers (RNE round, bit-level)
// ---------------------------------------------------------------------------
__device__ __forceinline__ unsigned short f2bf(float x) {
    unsigned int u = __float_as_uint(x);
    u += 0x7fffu + ((u >> 16) & 1u);
    return (unsigned short)(u >> 16);
}
__device__ __forceinline__ float bf2f(unsigned short b) {
    return __uint_as_float((unsigned int)b << 16);
}

// ---------------------------------------------------------------------------
// int64-vs-int32 edge storage detect for all 3 graphs in one launch
// ---------------------------------------------------------------------------
__global__ void detect3_k(const int* __restrict__ a, const int* __restrict__ b,
                          const int* __restrict__ c, int n_check,
                          int* __restrict__ modes) {
    const int* e = (blockIdx.x == 0) ? a : (blockIdx.x == 1) ? b : c;
    __shared__ int any_nz;
    if (threadIdx.x == 0) any_nz = 0;
    __syncthreads();
    for (int i = threadIdx.x; i < n_check; i += blockDim.x) {
        if (e[2 * i + 1] != 0) atomicOr(&any_nz, 1);
    }
    __syncthreads();
    if (threadIdx.x == 0) modes[blockIdx.x] = any_nz ? 0 : 1;
}

// ---------------------------------------------------------------------------
// Pass 1: radix-bin edges by dst>>RSH (payload pack: s | d_local<<17) and by
// src>>RSH (payload: s_local ushort). R0-R2 lesson: the preprocess was bound
// at ~22G scattered-atomic/store ops/s on the fabric, invariant to cache
// locality tweaks. This pass replaces 3.2M global atomics + 1.6M random 4B
// stores with LDS histograms + ~150K global atomics + append-clustered writes.
// ---------------------------------------------------------------------------
__global__ __launch_bounds__(256) void bin_k(const int* __restrict__ e32, int E,
                                             const int* __restrict__ mode_p,
                                             int* __restrict__ binCntD,
                                             int* __restrict__ binCntS,
                                             unsigned int* __restrict__ binBufD,
                                             unsigned short* __restrict__ binBufS,
                                             int B) {
    __shared__ int hcD[MAXB], hcS[MAXB];
    __shared__ int baseD[MAXB], baseS[MAXB];
    const int t = threadIdx.x;
    for (int i = t; i < B; i += 256) { hcD[i] = 0; hcS[i] = 0; }
    __syncthreads();

    int s[16], d[16];
    const long long e0 = (long long)blockIdx.x * CHUNK;
    const int mode = *mode_p;

    if (mode) {  // int64 storage, values fit in low word
        const long long* __restrict__ s64 = (const long long*)e32;
        const long long* __restrict__ d64 = s64 + E;
#pragma unroll
        for (int j = 0; j < 16; ++j) {
            long long idx = e0 + j * 256 + t;
            if (idx < E) { s[j] = (int)s64[idx]; d[j] = (int)d64[idx]; }
            else         { s[j] = -1; d[j] = -1; }
        }
    } else {     // int32 storage
        const int* __restrict__ s32 = e32;
        const int* __restrict__ d32 = e32 + E;
#pragma unroll
        for (int j = 0; j < 16; ++j) {
            long long idx = e0 + j * 256 + t;
            if (idx < E) { s[j] = s32[idx]; d[j] = d32[idx]; }
            else         { s[j] = -1; d[j] = -1; }
        }
    }

    // count
#pragma unroll
    for (int j = 0; j < 16; ++j) {
        if (d[j] >= 0) {
            atomicAdd(&hcD[d[j] >> RSH], 1);
            atomicAdd(&hcS[s[j] >> RSH], 1);
        }
    }
    __syncthreads();

    // reserve global space per bin; reset hc for reuse as local offsets
    for (int i = t; i < B; i += 256) {
        int c = hcD[i];
        baseD[i] = c ? atomicAdd(&binCntD[i], c) : 0;
        hcD[i] = 0;
        c = hcS[i];
        baseS[i] = c ? atomicAdd(&binCntS[i], c) : 0;
        hcS[i] = 0;
    }
    __syncthreads();

    // place
#pragma unroll
    for (int j = 0; j < 16; ++j) {
        if (d[j] >= 0) {
            int bD = d[j] >> RSH;
            int p = atomicAdd(&hcD[bD], 1) + baseD[bD];
            if (p < CAPB)
                binBufD[(size_t)bD * CAPB + p] =
                    (unsigned int)s[j] | ((unsigned int)(d[j] & (RANGE - 1)) << 17);
            int bS = s[j] >> RSH;
            int q = atomicAdd(&hcS[bS], 1) + baseS[bS];
            if (q < CAPB)
                binBufS[(size_t)bS * CAPB + q] = (unsigned short)(s[j] & (RANGE - 1));
        }
    }
}

// ---------------------------------------------------------------------------
// Pass 2: blocks [0,B) build dst-adjacency in LDS (atomics at LDS speed),
// then stream bucket rows + true cnt out coalesced. Blocks [B,2B) histogram
// src-bins in LDS and write deg_out coalesced.
// ---------------------------------------------------------------------------
__global__ __launch_bounds__(256) void build_k(const int* __restrict__ binCntD,
                                               const int* __restrict__ binCntS,
                                               const unsigned int* __restrict__ binBufD,
                                               const unsigned short* __restrict__ binBufS,
                                               int* __restrict__ bucket,
                                               int* __restrict__ cnt,
                                               int* __restrict__ deg_out,
                                               int B, int N) {
    __shared__ int lcnt[RANGE];
    __shared__ int lbuf[RANGE * CAP];   // 98KB
    const int t = threadIdx.x;

    if ((int)blockIdx.x < B) {
        const int bin = blockIdx.x;
        for (int i = t; i < RANGE; i += 256) lcnt[i] = 0;
        __syncthreads();
        const int nE = min(binCntD[bin], CAPB);
        const unsigned int* __restrict__ src = binBufD + (size_t)bin * CAPB;
        for (int i = t; i < nE; i += 256) {
            unsigned int v = src[i];
            int dl = v >> 17;
            int p = atomicAdd(&lcnt[dl], 1);
            if (p < CAP) lbuf[dl * CAP + p] = (int)(v & 0x1FFFFu);
        }
        __syncthreads();
        const int node0 = bin * RANGE;
        const int nn = min(RANGE, N - node0);
        for (int i = t; i < nn; i += 256) cnt[node0 + i] = lcnt[i];
        for (int i = t; i < nn * CAP; i += 256)
            bucket[(size_t)node0 * CAP + i] = lbuf[i];
    } else {
        const int bin = blockIdx.x - B;
        for (int i = t; i < RANGE; i += 256) lcnt[i] = 0;
        __syncthreads();
        const int nE = min(binCntS[bin], CAPB);
        const unsigned short* __restrict__ src = binBufS + (size_t)bin * CAPB;
        for (int i = t; i < nE; i += 256) atomicAdd(&lcnt[src[i]], 1);
        __syncthreads();
        const int node0 = bin * RANGE;
        const int nn = min(RANGE, N - node0);
        for (int i = t; i < nn; i += 256) deg_out[node0 + i] = lcnt[i];
    }
}

// ---------------------------------------------------------------------------
// bf16-split MFMA GEMM:
//   Hout[row][0:128] = bf16( (X[row][0:K] @ W[K][128]) * clip(deg,1)^-1/2 )
// ---------------------------------------------------------------------------
__global__ __launch_bounds__(256) void gemm_split_k(const float* __restrict__ X,
                                                    const float* __restrict__ W,
                                                    const int* __restrict__ deg,
                                                    unsigned short* __restrict__ Hout,
                                                    int M, int K) {
    __shared__ __align__(16) unsigned short As_hi[128 * 32];
    __shared__ __align__(16) unsigned short As_lo[128 * 32];
    __shared__ __align__(16) unsigned short Bs_hi[128 * 32];
    __shared__ __align__(16) unsigned short Bs_lo[128 * 32];

    const int tid = threadIdx.x;
    const int lane = tid & 63;
    const int w = tid >> 6;
    const int wr = w >> 1, wc = w & 1;
    const int bm = blockIdx.x * 128;
    const int l15 = lane & 15, l4 = lane >> 4;

    f32x4 acc[4][4];
#pragma unroll
    for (int m = 0; m < 4; ++m)
#pragma unroll
        for (int n = 0; n < 4; ++n) acc[m][n] = (f32x4){0.f, 0.f, 0.f, 0.f};

    for (int k0 = 0; k0 < K; k0 += 32) {
#pragma unroll
        for (int i = 0; i < 4; ++i) {
            int idx = tid + i * 256;
            int r = idx >> 3;
            int kq = idx & 7;
            float4 v = make_float4(0.f, 0.f, 0.f, 0.f);
            if (bm + r < M) v = *(const float4*)&X[(size_t)(bm + r) * K + k0 + kq * 4];
            ushort4 h, l;
            h.x = f2bf(v.x); l.x = f2bf(v.x - bf2f(h.x));
            h.y = f2bf(v.y); l.y = f2bf(v.y - bf2f(h.y));
            h.z = f2bf(v.z); l.z = f2bf(v.z - bf2f(h.z));
            h.w = f2bf(v.w); l.w = f2bf(v.w - bf2f(h.w));
            *(ushort4*)&As_hi[r * 32 + kq * 4] = h;
            *(ushort4*)&As_lo[r * 32 + kq * 4] = l;
        }
        {
            int col = tid & 127;
            int kh = tid >> 7;
            unsigned short hi[16], lo[16];
#pragma unroll
            for (int j = 0; j < 16; ++j) {
                float v = W[(size_t)(k0 + kh * 16 + j) * 128 + col];
                hi[j] = f2bf(v);
                lo[j] = f2bf(v - bf2f(hi[j]));
            }
            short8 ph0, ph1, pl0, pl1;
#pragma unroll
            for (int j = 0; j < 8; ++j) {
                ph0[j] = (short)hi[j]; ph1[j] = (short)hi[j + 8];
                pl0[j] = (short)lo[j]; pl1[j] = (short)lo[j + 8];
            }
            *(short8*)&Bs_hi[col * 32 + kh * 16 + 0] = ph0;
            *(short8*)&Bs_hi[col * 32 + kh * 16 + 8] = ph1;
            *(short8*)&Bs_lo[col * 32 + kh * 16 + 0] = pl0;
            *(short8*)&Bs_lo[col * 32 + kh * 16 + 8] = pl1;
        }
        __syncthreads();

        short8 ah[4], al[4], bh[4], bl[4];
#pragma unroll
        for (int m = 0; m < 4; ++m) {
            int row = wr * 64 + m * 16 + l15;
            ah[m] = *(const short8*)&As_hi[row * 32 + l4 * 8];
            al[m] = *(const short8*)&As_lo[row * 32 + l4 * 8];
        }
#pragma unroll
        for (int n = 0; n < 4; ++n) {
            int col = wc * 64 + n * 16 + l15;
            bh[n] = *(const short8*)&Bs_hi[col * 32 + l4 * 8];
            bl[n] = *(const short8*)&Bs_lo[col * 32 + l4 * 8];
        }

#pragma unroll
        for (int m = 0; m < 4; ++m)
#pragma unroll
            for (int n = 0; n < 4; ++n) {
                acc[m][n] = __builtin_amdgcn_mfma_f32_16x16x32_bf16(ah[m], bh[n], acc[m][n], 0, 0, 0);
                acc[m][n] = __builtin_amdgcn_mfma_f32_16x16x32_bf16(al[m], bh[n], acc[m][n], 0, 0, 0);
                acc[m][n] = __builtin_amdgcn_mfma_f32_16x16x32_bf16(ah[m], bl[n], acc[m][n], 0, 0, 0);
            }
        __syncthreads();
    }

    // C/D layout: col = lane&15, row = (lane>>4)*4 + reg  [m89/m91-verified]
#pragma unroll
    for (int m = 0; m < 4; ++m) {
#pragma unroll
        for (int i = 0; i < 4; ++i) {
            int row = bm + wr * 64 + m * 16 + l4 * 4 + i;
            if (row < M) {
                int dg = deg[row];
                float sc = rsqrtf((float)(dg > 1 ? dg : 1));
#pragma unroll
                for (int n = 0; n < 4; ++n) {
                    int col = wc * 64 + n * 16 + l15;
                    Hout[(size_t)row * 128 + col] = f2bf(acc[m][n][i] * sc);
                }
            }
        }
    }
}

// ---------------------------------------------------------------------------
// SpMM over buckets: out[n][:] = (sum_j bf16h[bucket[n][j]][:]) * deg^-1/2 + b
// ---------------------------------------------------------------------------
__global__ __launch_bounds__(256) void spmm_k(const int* __restrict__ cnt,
                                              const int* __restrict__ bucket,
                                              const unsigned int* __restrict__ h32,
                                              const float* __restrict__ bias,
                                              float* __restrict__ out,
                                              int do_relu, int N) {
    const int lane = threadIdx.x & 63;
    const int n = blockIdx.x * 4 + (threadIdx.x >> 6);
    if (n >= N) return;
    const int deg = cnt[n];
    const int e1 = deg < CAP ? deg : CAP;
    const int* __restrict__ bk = bucket + (size_t)n * CAP;
    float a0 = 0.f, a1 = 0.f;
    int e = 0;
    for (; e + 4 <= e1; e += 4) {
        int s0 = bk[e + 0], s1 = bk[e + 1], s2 = bk[e + 2], s3 = bk[e + 3];
        unsigned int v0 = h32[(size_t)s0 * 64 + lane];
        unsigned int v1 = h32[(size_t)s1 * 64 + lane];
        unsigned int v2 = h32[(size_t)s2 * 64 + lane];
        unsigned int v3 = h32[(size_t)s3 * 64 + lane];
        a0 += __uint_as_float(v0 << 16) + __uint_as_float(v1 << 16) +
              __uint_as_float(v2 << 16) + __uint_as_float(v3 << 16);
        a1 += __uint_as_float(v0 & 0xffff0000u) + __uint_as_float(v1 & 0xffff0000u) +
              __uint_as_float(v2 & 0xffff0000u) + __uint_as_float(v3 & 0xffff0000u);
    }
    for (; e < e1; ++e) {
        unsigned int v = h32[(size_t)bk[e] * 64 + lane];
        a0 += __uint_as_float(v << 16);
        a1 += __uint_as_float(v & 0xffff0000u);
    }
    float sc = rsqrtf((float)(deg > 1 ? deg : 1));
    float bx = bias[2 * lane], by = bias[2 * lane + 1];
    float r0 = a0 * sc + bx;
    float r1 = a1 * sc + by;
    if (do_relu) { r0 = fmaxf(r0, 0.f); r1 = fmaxf(r1, 0.f); }
    float2 o; o.x = r0; o.y = r1;
    *(float2*)&out[(size_t)n * 128 + 2 * lane] = o;
}

// ---------------------------------------------------------------------------
// launcher
// ---------------------------------------------------------------------------
extern "C" void kernel_launch(void* const* d_in, const int* in_sizes, int n_in,
                              void* d_out, int out_size, void* d_ws, size_t ws_size,
                              hipStream_t stream) {
    const int E = in_sizes[0] / 2;        // 1,600,000
    const int N = in_sizes[1] / IN_DIM;   // 100,000

    const float* W0 = (const float*)d_in[6];
    const float* b0 = (const float*)d_in[7];
    const float* W1 = (const float*)d_in[8];
    const float* b1 = (const float*)d_in[9];
    float* out = (float*)d_out;

    char* ws = (char*)d_ws;
    size_t off = 0;
    auto alloc = [&](size_t bytes) -> void* {
        void* p = ws + off;
        off += (bytes + 255) & ~(size_t)255;
        return p;
    };
    const int B = (N + RANGE - 1) >> RSH;               // 196 bins
    const size_t Nw = (((size_t)N * 4 + 255) & ~(size_t)255) / 4;  // ints, rounded

    unsigned short* hbuf = (unsigned short*)alloc((size_t)N * HID * 2);  // 25.6MB
    float* x1    = (float*)alloc((size_t)N * HID * 4);                   // 51.2MB
    int* bucket  = (int*)alloc((size_t)N * CAP * 4);                     // 19.2MB
    int* counts  = (int*)alloc((2 * Nw + 2 * MAXB) * 4);  // deg_out|cnt|binCntD|binCntS
    unsigned int*   binBufD = (unsigned int*)alloc((size_t)B * CAPB * 4);    // 8.0MB
    unsigned short* binBufS = (unsigned short*)alloc((size_t)B * CAPB * 2);  // 4.0MB
    int* modes   = (int*)alloc(256);

    int* deg_out = counts;
    int* cnt     = counts + Nw;
    int* binCntD = counts + 2 * Nw;
    int* binCntS = binCntD + MAXB;
    const size_t counts_bytes = (2 * Nw + 2 * MAXB) * 4;

    const int gemm_blocks = (N + 127) / 128;
    const int spmm_blocks = (N + 3) / 4;
    const int bin_blocks  = (E + CHUNK - 1) / CHUNK;

    // one detect launch for all three graphs
    detect3_k<<<3, 256, 0, stream>>>((const int*)d_in[0], (const int*)d_in[2],
                                     (const int*)d_in[4], 2048, modes);

    for (int g = 0; g < 3; ++g) {
        const int* e32 = (const int*)d_in[g * 2];
        const float* X = (const float*)d_in[g * 2 + 1];
        float* zout = out + (size_t)g * N * HID;
        const int K1 = in_sizes[g * 2 + 1] / N;  // 256

        hipMemsetAsync(counts, 0, counts_bytes, stream);
        bin_k<<<bin_blocks, 256, 0, stream>>>(e32, E, modes + g,
                                              binCntD, binCntS, binBufD, binBufS, B);
        build_k<<<2 * B, 256, 0, stream>>>(binCntD, binCntS, binBufD, binBufS,
                                           bucket, cnt, deg_out, B, N);

        // layer 1
        gemm_split_k<<<gemm_blocks, 256, 0, stream>>>(X, W0, deg_out, hbuf, N, K1);
        spmm_k<<<spmm_blocks, 256, 0, stream>>>(cnt, bucket, (const unsigned int*)hbuf, b0, x1, 1, N);

        // layer 2
        gemm_split_k<<<gemm_blocks, 256, 0, stream>>>(x1, W1, deg_out, hbuf, N, HID);
        spmm_k<<<spmm_blocks, 256, 0, stream>>>(cnt, bucket, (const unsigned int*)hbuf, b1, zout, 0, N);
    }
}

// Round 4
// 892.892 us; speedup vs baseline: 1.3364x; 1.0465x over previous
//
#include <hip/hip_runtime.h>

#define IN_DIM 256
#define HID 128
#define CAP 48        // bucket capacity per node; P(Poisson(16) >= 48) ~ 1e-30
#define RANGE 512     // nodes per bin (dst>>9); LDS adjacency 512*48*4 = 96KB
#define RSH 9
#define MAXB 256      // max bins supported (N <= 131072; also s fits 17 bits)
#define CAPB 10240    // per-bin edge capacity (~8163 avg, 25% slack)
#define CHUNK 4096    // edges per bin_k workgroup (256 thr * 16)

using short8 = __attribute__((ext_vector_type(8))) short;
using f32x4  = __attribute__((ext_vector_type(4))) float;

// ---------------------------------------------------------------------------
// bf16 helpers (RNE round, bit-level)
// ---------------------------------------------------------------------------
__device__ __forceinline__ unsigned short f2bf(float x) {
    unsigned int u = __float_as_uint(x);
    u += 0x7fffu + ((u >> 16) & 1u);
    return (unsigned short)(u >> 16);
}
__device__ __forceinline__ float bf2f(unsigned short b) {
    return __uint_as_float((unsigned int)b << 16);
}

// ---------------------------------------------------------------------------
// int64-vs-int32 edge storage detect for all 3 graphs in one launch
// ---------------------------------------------------------------------------
__global__ void detect3_k(const int* __restrict__ a, const int* __restrict__ b,
                          const int* __restrict__ c, int n_check,
                          int* __restrict__ modes) {
    const int* e = (blockIdx.x == 0) ? a : (blockIdx.x == 1) ? b : c;
    __shared__ int any_nz;
    if (threadIdx.x == 0) any_nz = 0;
    __syncthreads();
    for (int i = threadIdx.x; i < n_check; i += blockDim.x) {
        if (e[2 * i + 1] != 0) atomicOr(&any_nz, 1);
    }
    __syncthreads();
    if (threadIdx.x == 0) modes[blockIdx.x] = any_nz ? 0 : 1;
}

// ---------------------------------------------------------------------------
// One-time weight prep: W[K][128] fp32 -> transposed bf16 hi/lo planes
// W*T[col][k].  Removes per-block per-K-step W conversion from the GEMM
// (R3: that + the Bs 32-way-conflict staging write was the GEMM overhead).
// ---------------------------------------------------------------------------
__global__ __launch_bounds__(256) void prep_w_k(const float* __restrict__ W0,
                                                const float* __restrict__ W1,
                                                unsigned short* __restrict__ W0hiT,
                                                unsigned short* __restrict__ W0loT,
                                                unsigned short* __restrict__ W1hiT,
                                                unsigned short* __restrict__ W1loT) {
    int gid = blockIdx.x * 256 + threadIdx.x;
    if (gid < IN_DIM * HID) {
        int k = gid >> 7, c = gid & 127;
        float v = W0[gid];
        unsigned short h = f2bf(v), l = f2bf(v - bf2f(h));
        W0hiT[(size_t)c * IN_DIM + k] = h;
        W0loT[(size_t)c * IN_DIM + k] = l;
    } else if (gid < IN_DIM * HID + HID * HID) {
        int g2 = gid - IN_DIM * HID;
        int k = g2 >> 7, c = g2 & 127;
        float v = W1[g2];
        unsigned short h = f2bf(v), l = f2bf(v - bf2f(h));
        W1hiT[(size_t)c * HID + k] = h;
        W1loT[(size_t)c * HID + k] = l;
    }
}

// ---------------------------------------------------------------------------
// Pass 1: radix-bin edges by dst>>RSH (payload pack: s | d_local<<17) and by
// src>>RSH (payload: s_local ushort). Replaces 3.2M global atomics + 1.6M
// random 4B stores with LDS histograms + ~150K global atomics + clustered
// appends (R3: 143us -> bin+build well under the old preprocess).
// ---------------------------------------------------------------------------
__global__ __launch_bounds__(256) void bin_k(const int* __restrict__ e32, int E,
                                             const int* __restrict__ mode_p,
                                             int* __restrict__ binCntD,
                                             int* __restrict__ binCntS,
                                             unsigned int* __restrict__ binBufD,
                                             unsigned short* __restrict__ binBufS,
                                             int B) {
    __shared__ int hcD[MAXB], hcS[MAXB];
    __shared__ int baseD[MAXB], baseS[MAXB];
    const int t = threadIdx.x;
    for (int i = t; i < B; i += 256) { hcD[i] = 0; hcS[i] = 0; }
    __syncthreads();

    int s[16], d[16];
    const long long e0 = (long long)blockIdx.x * CHUNK;
    const int mode = *mode_p;

    if (mode) {  // int64 storage, values fit in low word
        const long long* __restrict__ s64 = (const long long*)e32;
        const long long* __restrict__ d64 = s64 + E;
#pragma unroll
        for (int j = 0; j < 16; ++j) {
            long long idx = e0 + j * 256 + t;
            if (idx < E) { s[j] = (int)s64[idx]; d[j] = (int)d64[idx]; }
            else         { s[j] = -1; d[j] = -1; }
        }
    } else {     // int32 storage
        const int* __restrict__ s32 = e32;
        const int* __restrict__ d32 = e32 + E;
#pragma unroll
        for (int j = 0; j < 16; ++j) {
            long long idx = e0 + j * 256 + t;
            if (idx < E) { s[j] = s32[idx]; d[j] = d32[idx]; }
            else         { s[j] = -1; d[j] = -1; }
        }
    }

    // count
#pragma unroll
    for (int j = 0; j < 16; ++j) {
        if (d[j] >= 0) {
            atomicAdd(&hcD[d[j] >> RSH], 1);
            atomicAdd(&hcS[s[j] >> RSH], 1);
        }
    }
    __syncthreads();

    // reserve global space per bin; reset hc for reuse as local offsets
    for (int i = t; i < B; i += 256) {
        int c = hcD[i];
        baseD[i] = c ? atomicAdd(&binCntD[i], c) : 0;
        hcD[i] = 0;
        c = hcS[i];
        baseS[i] = c ? atomicAdd(&binCntS[i], c) : 0;
        hcS[i] = 0;
    }
    __syncthreads();

    // place
#pragma unroll
    for (int j = 0; j < 16; ++j) {
        if (d[j] >= 0) {
            int bD = d[j] >> RSH;
            int p = atomicAdd(&hcD[bD], 1) + baseD[bD];
            if (p < CAPB)
                binBufD[(size_t)bD * CAPB + p] =
                    (unsigned int)s[j] | ((unsigned int)(d[j] & (RANGE - 1)) << 17);
            int bS = s[j] >> RSH;
            int q = atomicAdd(&hcS[bS], 1) + baseS[bS];
            if (q < CAPB)
                binBufS[(size_t)bS * CAPB + q] = (unsigned short)(s[j] & (RANGE - 1));
        }
    }
}

// ---------------------------------------------------------------------------
// Pass 2: blocks [0,B) build dst-adjacency in LDS (atomics at LDS speed),
// then stream bucket rows + true cnt out coalesced. Blocks [B,2B) histogram
// src-bins in LDS and write deg_out coalesced.
// NOTE: writes cnt/deg_out for ALL nodes -> no global memset needed for them.
// ---------------------------------------------------------------------------
__global__ __launch_bounds__(256) void build_k(const int* __restrict__ binCntD,
                                               const int* __restrict__ binCntS,
                                               const unsigned int* __restrict__ binBufD,
                                               const unsigned short* __restrict__ binBufS,
                                               int* __restrict__ bucket,
                                               int* __restrict__ cnt,
                                               int* __restrict__ deg_out,
                                               int B, int N) {
    __shared__ int lcnt[RANGE];
    __shared__ int lbuf[RANGE * CAP];   // 96KB
    const int t = threadIdx.x;

    if ((int)blockIdx.x < B) {
        const int bin = blockIdx.x;
        for (int i = t; i < RANGE; i += 256) lcnt[i] = 0;
        __syncthreads();
        const int nE = min(binCntD[bin], CAPB);
        const unsigned int* __restrict__ src = binBufD + (size_t)bin * CAPB;
        for (int i = t; i < nE; i += 256) {
            unsigned int v = src[i];
            int dl = v >> 17;
            int p = atomicAdd(&lcnt[dl], 1);
            if (p < CAP) lbuf[dl * CAP + p] = (int)(v & 0x1FFFFu);
        }
        __syncthreads();
        const int node0 = bin * RANGE;
        const int nn = min(RANGE, N - node0);
        for (int i = t; i < nn; i += 256) cnt[node0 + i] = lcnt[i];
        for (int i = t; i < nn * CAP; i += 256)
            bucket[(size_t)node0 * CAP + i] = lbuf[i];
    } else {
        const int bin = blockIdx.x - B;
        for (int i = t; i < RANGE; i += 256) lcnt[i] = 0;
        __syncthreads();
        const int nE = min(binCntS[bin], CAPB);
        const unsigned short* __restrict__ src = binBufS + (size_t)bin * CAPB;
        for (int i = t; i < nE; i += 256) atomicAdd(&lcnt[src[i]], 1);
        __syncthreads();
        const int node0 = bin * RANGE;
        const int nn = min(RANGE, N - node0);
        for (int i = t; i < nn; i += 256) deg_out[node0 + i] = lcnt[i];
    }
}

// ---------------------------------------------------------------------------
// bf16-split MFMA GEMM v2:
//   Hout[row][0:128] = bf16( (X[row][0:K] @ W[K][128]) * clip(deg,1)^-1/2 )
// R3 profile: MfmaUtil 8.4%, 4M LDS bank conflicts (the Bs staging write was
// a 32-way conflict), W re-converted per block per step, 2 barriers/step.
// v2: B fragments load directly from pre-converted transposed global planes
// (L2-resident 128KB); As double-buffered with register prefetch -> 1 barrier
// per K-step. As stage/read patterns verified conflict-free at stride 32.
// ---------------------------------------------------------------------------
__global__ __launch_bounds__(256) void gemm_v2_k(const float* __restrict__ X,
                                                 const unsigned short* __restrict__ BhiT,
                                                 const unsigned short* __restrict__ BloT,
                                                 const int* __restrict__ deg,
                                                 unsigned short* __restrict__ Hout,
                                                 int M, int K) {
    __shared__ __align__(16) unsigned short As[2][2][128 * 32];  // [buf][hi/lo]

    const int tid = threadIdx.x;
    const int lane = tid & 63;
    const int w = tid >> 6;
    const int wr = w >> 1, wc = w & 1;
    const int bm = blockIdx.x * 128;
    const int l15 = lane & 15, l4 = lane >> 4;
    const int r0 = tid >> 3;   // staging row base (this thread covers r0+32i)
    const int kq = tid & 7;    // float4 slot within the 32-wide k panel

    f32x4 acc[4][4];
#pragma unroll
    for (int m = 0; m < 4; ++m)
#pragma unroll
        for (int n = 0; n < 4; ++n) acc[m][n] = (f32x4){0.f, 0.f, 0.f, 0.f};

    float4 pf[4];

#define LOADT(k0)                                                              \
    {                                                                          \
        _Pragma("unroll")                                                      \
        for (int i = 0; i < 4; ++i) {                                          \
            int r = r0 + i * 32;                                               \
            pf[i] = make_float4(0.f, 0.f, 0.f, 0.f);                           \
            if (bm + r < M)                                                    \
                pf[i] = *(const float4*)&X[(size_t)(bm + r) * K + (k0) + kq * 4]; \
        }                                                                      \
    }

#define STORET(buf)                                                            \
    {                                                                          \
        _Pragma("unroll")                                                      \
        for (int i = 0; i < 4; ++i) {                                          \
            int r = r0 + i * 32;                                               \
            ushort4 h, l;                                                      \
            h.x = f2bf(pf[i].x); l.x = f2bf(pf[i].x - bf2f(h.x));              \
            h.y = f2bf(pf[i].y); l.y = f2bf(pf[i].y - bf2f(h.y));              \
            h.z = f2bf(pf[i].z); l.z = f2bf(pf[i].z - bf2f(h.z));              \
            h.w = f2bf(pf[i].w); l.w = f2bf(pf[i].w - bf2f(h.w));              \
            *(ushort4*)&As[buf][0][r * 32 + kq * 4] = h;                       \
            *(ushort4*)&As[buf][1][r * 32 + kq * 4] = l;                       \
        }                                                                      \
    }

    LOADT(0);
    STORET(0);
    __syncthreads();

    const int NS = K >> 5;
    for (int s = 0; s < NS; ++s) {
        const int buf = s & 1;
        if (s + 1 < NS) LOADT((s + 1) << 5);

        short8 ah[4], al[4], bh[4], bl[4];
#pragma unroll
        for (int m = 0; m < 4; ++m) {
            int row = wr * 64 + m * 16 + l15;
            ah[m] = *(const short8*)&As[buf][0][row * 32 + l4 * 8];
            al[m] = *(const short8*)&As[buf][1][row * 32 + l4 * 8];
        }
        const int kb = (s << 5) + l4 * 8;
#pragma unroll
        for (int n = 0; n < 4; ++n) {
            int col = wc * 64 + n * 16 + l15;
            bh[n] = *(const short8*)&BhiT[(size_t)col * K + kb];
            bl[n] = *(const short8*)&BloT[(size_t)col * K + kb];
        }

        // hi*hi + lo*hi + hi*lo
#pragma unroll
        for (int m = 0; m < 4; ++m)
#pragma unroll
            for (int n = 0; n < 4; ++n) {
                acc[m][n] = __builtin_amdgcn_mfma_f32_16x16x32_bf16(ah[m], bh[n], acc[m][n], 0, 0, 0);
                acc[m][n] = __builtin_amdgcn_mfma_f32_16x16x32_bf16(al[m], bh[n], acc[m][n], 0, 0, 0);
                acc[m][n] = __builtin_amdgcn_mfma_f32_16x16x32_bf16(ah[m], bl[n], acc[m][n], 0, 0, 0);
            }

        if (s + 1 < NS) STORET(buf ^ 1);
        __syncthreads();
    }
#undef LOADT
#undef STORET

    // ---- epilogue: scale by deg_out^{-1/2}, store bf16 ----
    // C/D layout: col = lane&15, row = (lane>>4)*4 + reg  [m89/m91-verified]
#pragma unroll
    for (int m = 0; m < 4; ++m) {
#pragma unroll
        for (int i = 0; i < 4; ++i) {
            int row = bm + wr * 64 + m * 16 + l4 * 4 + i;
            if (row < M) {
                int dg = deg[row];
                float sc = rsqrtf((float)(dg > 1 ? dg : 1));
#pragma unroll
                for (int n = 0; n < 4; ++n) {
                    int col = wc * 64 + n * 16 + l15;
                    Hout[(size_t)row * 128 + col] = f2bf(acc[m][n][i] * sc);
                }
            }
        }
    }
}

// ---------------------------------------------------------------------------
// SpMM over buckets: out[n][:] = (sum_j bf16h[bucket[n][j]][:]) * deg^-1/2 + b
// ---------------------------------------------------------------------------
__global__ __launch_bounds__(256) void spmm_k(const int* __restrict__ cnt,
                                              const int* __restrict__ bucket,
                                              const unsigned int* __restrict__ h32,
                                              const float* __restrict__ bias,
                                              float* __restrict__ out,
                                              int do_relu, int N) {
    const int lane = threadIdx.x & 63;
    const int n = blockIdx.x * 4 + (threadIdx.x >> 6);
    if (n >= N) return;
    const int deg = cnt[n];
    const int e1 = deg < CAP ? deg : CAP;
    const int* __restrict__ bk = bucket + (size_t)n * CAP;
    float a0 = 0.f, a1 = 0.f;
    int e = 0;
    for (; e + 4 <= e1; e += 4) {
        int s0 = bk[e + 0], s1 = bk[e + 1], s2 = bk[e + 2], s3 = bk[e + 3];
        unsigned int v0 = h32[(size_t)s0 * 64 + lane];
        unsigned int v1 = h32[(size_t)s1 * 64 + lane];
        unsigned int v2 = h32[(size_t)s2 * 64 + lane];
        unsigned int v3 = h32[(size_t)s3 * 64 + lane];
        a0 += __uint_as_float(v0 << 16) + __uint_as_float(v1 << 16) +
              __uint_as_float(v2 << 16) + __uint_as_float(v3 << 16);
        a1 += __uint_as_float(v0 & 0xffff0000u) + __uint_as_float(v1 & 0xffff0000u) +
              __uint_as_float(v2 & 0xffff0000u) + __uint_as_float(v3 & 0xffff0000u);
    }
    for (; e < e1; ++e) {
        unsigned int v = h32[(size_t)bk[e] * 64 + lane];
        a0 += __uint_as_float(v << 16);
        a1 += __uint_as_float(v & 0xffff0000u);
    }
    float sc = rsqrtf((float)(deg > 1 ? deg : 1));
    float bx = bias[2 * lane], by = bias[2 * lane + 1];
    float r0 = a0 * sc + bx;
    float r1 = a1 * sc + by;
    if (do_relu) { r0 = fmaxf(r0, 0.f); r1 = fmaxf(r1, 0.f); }
    float2 o; o.x = r0; o.y = r1;
    *(float2*)&out[(size_t)n * 128 + 2 * lane] = o;
}

// ---------------------------------------------------------------------------
// launcher
// ---------------------------------------------------------------------------
extern "C" void kernel_launch(void* const* d_in, const int* in_sizes, int n_in,
                              void* d_out, int out_size, void* d_ws, size_t ws_size,
                              hipStream_t stream) {
    const int E = in_sizes[0] / 2;        // 1,600,000
    const int N = in_sizes[1] / IN_DIM;   // 100,000

    const float* W0 = (const float*)d_in[6];
    const float* b0 = (const float*)d_in[7];
    const float* W1 = (const float*)d_in[8];
    const float* b1 = (const float*)d_in[9];
    float* out = (float*)d_out;

    char* ws = (char*)d_ws;
    size_t off = 0;
    auto alloc = [&](size_t bytes) -> void* {
        void* p = ws + off;
        off += (bytes + 255) & ~(size_t)255;
        return p;
    };
    const int B = (N + RANGE - 1) >> RSH;               // 196 bins

    unsigned short* hbuf = (unsigned short*)alloc((size_t)N * HID * 2);  // 25.6MB
    float* x1    = (float*)alloc((size_t)N * HID * 4);                   // 51.2MB
    int* bucket  = (int*)alloc((size_t)N * CAP * 4);                     // 19.2MB
    int* counts  = (int*)alloc((size_t)2 * N * 4);       // deg_out | cnt (no memset needed)
    int* binCnt  = (int*)alloc(2 * MAXB * 4);            // binCntD | binCntS
    unsigned int*   binBufD = (unsigned int*)alloc((size_t)B * CAPB * 4);    // 8.0MB
    unsigned short* binBufS = (unsigned short*)alloc((size_t)B * CAPB * 2);  // 4.0MB
    unsigned short* W0hiT = (unsigned short*)alloc((size_t)IN_DIM * HID * 2);
    unsigned short* W0loT = (unsigned short*)alloc((size_t)IN_DIM * HID * 2);
    unsigned short* W1hiT = (unsigned short*)alloc((size_t)HID * HID * 2);
    unsigned short* W1loT = (unsigned short*)alloc((size_t)HID * HID * 2);
    int* modes   = (int*)alloc(256);

    int* deg_out = counts;
    int* cnt     = counts + N;
    int* binCntD = binCnt;
    int* binCntS = binCnt + MAXB;

    const int gemm_blocks = (N + 127) / 128;
    const int spmm_blocks = (N + 3) / 4;
    const int bin_blocks  = (E + CHUNK - 1) / CHUNK;

    // one detect launch for all three graphs; one weight-prep for the session
    detect3_k<<<3, 256, 0, stream>>>((const int*)d_in[0], (const int*)d_in[2],
                                     (const int*)d_in[4], 2048, modes);
    prep_w_k<<<192, 256, 0, stream>>>(W0, W1, W0hiT, W0loT, W1hiT, W1loT);

    for (int g = 0; g < 3; ++g) {
        const int* e32 = (const int*)d_in[g * 2];
        const float* X = (const float*)d_in[g * 2 + 1];
        float* zout = out + (size_t)g * N * HID;
        const int K1 = in_sizes[g * 2 + 1] / N;  // 256

        hipMemsetAsync(binCnt, 0, 2 * MAXB * 4, stream);
        bin_k<<<bin_blocks, 256, 0, stream>>>(e32, E, modes + g,
                                              binCntD, binCntS, binBufD, binBufS, B);
        build_k<<<2 * B, 256, 0, stream>>>(binCntD, binCntS, binBufD, binBufS,
                                           bucket, cnt, deg_out, B, N);

        // layer 1
        gemm_v2_k<<<gemm_blocks, 256, 0, stream>>>(X, W0hiT, W0loT, deg_out, hbuf, N, K1);
        spmm_k<<<spmm_blocks, 256, 0, stream>>>(cnt, bucket, (const unsigned int*)hbuf, b0, x1, 1, N);

        // layer 2
        gemm_v2_k<<<gemm_blocks, 256, 0, stream>>>(x1, W1hiT, W1loT, deg_out, hbuf, N, HID);
        spmm_k<<<spmm_blocks, 256, 0, stream>>>(cnt, bucket, (const unsigned int*)hbuf, b1, zout, 0, N);
    }
}